// Round 1
// 391.362 us; speedup vs baseline: 1.0764x; 1.0764x over previous
//
#include <hip/hip_runtime.h>

#define TOK   16384
#define DIM   1024
#define INNER 4096
#define EPSF  1e-5f

typedef int v4i  __attribute__((ext_vector_type(4)));
typedef int v16i __attribute__((ext_vector_type(16)));

static __device__ __forceinline__ void async_copy16(const char* g, char* l) {
    __builtin_amdgcn_global_load_lds(
        (const __attribute__((address_space(1))) unsigned int*)g,
        (__attribute__((address_space(3))) unsigned int*)l, 16, 0, 0);
}

static __device__ __forceinline__ float bf2f(unsigned short u) {
    return __uint_as_float(((unsigned)u) << 16);
}
static __device__ __forceinline__ unsigned short f2bf(float f) {
    unsigned u = __float_as_uint(f);
    return (unsigned short)((u + 0x7fffu + ((u >> 16) & 1u)) >> 16);  // RNE
}

// erf via Abramowitz-Stegun 7.1.26, |abs err| <= 1.5e-7
static __device__ __forceinline__ float fast_erf(float z) {
    float az = fabsf(z);
    float tt = __builtin_amdgcn_rcpf(1.f + 0.3275911f * az);
    float poly = ((((1.061405429f * tt - 1.453152027f) * tt + 1.421413741f) * tt
                   - 0.284496736f) * tt + 0.254829592f) * tt;
    float er = 1.f - poly * __expf(-az * az);
    return copysignf(er, z);
}
static __device__ __forceinline__ float gelu_exact(float v) {
    return 0.5f * v * (1.f + fast_erf(v * 0.70710678118654752f));
}

static __device__ __forceinline__ float waveSum(float v) {
#pragma unroll
    for (int o = 32; o > 0; o >>= 1) v += __shfl_down(v, o, 64);
    return v;
}
static __device__ __forceinline__ float waveMax(float v) {
#pragma unroll
    for (int o = 32; o > 0; o >>= 1) v = fmaxf(v, __shfl_down(v, o, 64));
    return v;
}

// ---- per-tensor sum(|w|) reduction (f32 in) ----
__global__ void absmean_k(const float* __restrict__ w, int n4, float* __restrict__ acc) {
    int idx = blockIdx.x * blockDim.x + threadIdx.x;
    int stride = gridDim.x * blockDim.x;
    const float4* w4 = (const float4*)w;
    float s = 0.f;
    for (int i = idx; i < n4; i += stride) {
        float4 v = w4[i];
        s += fabsf(v.x) + fabsf(v.y) + fabsf(v.z) + fabsf(v.w);
    }
    __shared__ float sp[4];
    int wv = threadIdx.x >> 6, lane = threadIdx.x & 63;
    s = waveSum(s);
    if (lane == 0) sp[wv] = s;
    __syncthreads();
    if (threadIdx.x == 0) atomicAdd(acc, sp[0] + sp[1] + sp[2] + sp[3]);
}

// ---- per-tensor ternary quantize: wq = clip(round(w/clip(mean|w|,eps)),-1,1) ----
__global__ void wquant_k(const float* __restrict__ w, int n,
                         const float* __restrict__ acc, float* __restrict__ wscale,
                         char* __restrict__ wq) {
    float mean = *acc / (float)n;
    float cl = fmaxf(mean, EPSF);
    float s = 1.f / cl;
    if (blockIdx.x == 0 && threadIdx.x == 0) *wscale = cl;  // dequant factor
    int idx = blockIdx.x * blockDim.x + threadIdx.x;
    int stride = gridDim.x * blockDim.x;
    int n4 = n >> 2;
    const float4* w4 = (const float4*)w;
    unsigned* q4 = (unsigned*)wq;
    for (int i = idx; i < n4; i += stride) {
        float4 v = w4[i];
        float e[4] = {v.x, v.y, v.z, v.w};
        unsigned packed = 0;
#pragma unroll
        for (int j = 0; j < 4; j++) {
            float r = rintf(e[j] * s);
            r = fminf(fmaxf(r, -1.f), 1.f);
            packed |= ((unsigned)((int)r & 0xff)) << (8 * j);
        }
        q4[i] = packed;
    }
}

// ---- RMSNorm + per-token absmax int8 quant, f32 input. One block per row. ----
template <int D, int VPT>
__global__ void actquant_f32_k(const float* __restrict__ X, char* __restrict__ Q,
                               float* __restrict__ rs_out) {
    int token = blockIdx.x;
    int t = threadIdx.x;
    const float4* xp = (const float4*)(X + (long)token * D);
    float vals[VPT];
    float ss = 0.f, am = 0.f;
#pragma unroll
    for (int j = 0; j < VPT / 4; j++) {
        float4 v = xp[t * (VPT / 4) + j];
        vals[4 * j] = v.x; vals[4 * j + 1] = v.y; vals[4 * j + 2] = v.z; vals[4 * j + 3] = v.w;
        ss += v.x * v.x + v.y * v.y + v.z * v.z + v.w * v.w;
        am = fmaxf(am, fmaxf(fmaxf(fabsf(v.x), fabsf(v.y)), fmaxf(fabsf(v.z), fabsf(v.w))));
    }
    __shared__ float sp[8];
    __shared__ float bc[2];
    int wv = t >> 6, lane = t & 63;
    float S = waveSum(ss);
    float M = waveMax(am);
    if (lane == 0) { sp[wv] = S; sp[4 + wv] = M; }
    __syncthreads();
    if (t == 0) {
        float Sa = sp[0] + sp[1] + sp[2] + sp[3];
        float Ma = fmaxf(fmaxf(sp[4], sp[5]), fmaxf(sp[6], sp[7]));
        float rinv = rsqrtf(Sa * (1.f / (float)D) + EPSF);   // rsqrt(mean(x^2)+eps)
        float amn = Ma * rinv;                                // absmax of normalized row
        float scale = 127.f / fmaxf(amn, EPSF);
        rs_out[token] = 1.f / scale;                          // dequant factor
        bc[0] = rinv; bc[1] = scale;
    }
    __syncthreads();
    float rinv = bc[0], scale = bc[1];
    unsigned outw[VPT / 4];
#pragma unroll
    for (int j = 0; j < VPT; j++) {
        float r = rintf((vals[j] * rinv) * scale);
        r = fminf(fmaxf(r, -128.f), 127.f);
        unsigned qi = (unsigned)((int)r & 0xff) << (8 * (j & 3));
        if ((j & 3) == 0) outw[j / 4] = qi; else outw[j / 4] |= qi;
    }
    unsigned* qp = (unsigned*)(Q + (long)token * D);
#pragma unroll
    for (int j = 0; j < VPT / 4; j++) qp[t * (VPT / 4) + j] = outw[j];
}

// ---- GELU + RMSNorm + int8 quant, bf16 input (pre-activation h). ----
// GELU moved here from GEMM1's epilogue: this kernel is HBM-bound (192 MB stream)
// with ~30 idle VALU ops/value of headroom, so the erf is free here; in the
// MFMA-dense GEMM it was serial VALU tax.
template <int D, int VPT>  // VPT must be 16
__global__ void actquant_bf16_k(const unsigned short* __restrict__ X, char* __restrict__ Q,
                                float* __restrict__ rs_out) {
    int token = blockIdx.x;
    int t = threadIdx.x;
    const uint4* xp = (const uint4*)(X + (long)token * D);
    float vals[VPT];
    float ss = 0.f, am = 0.f;
#pragma unroll
    for (int j = 0; j < VPT / 8; j++) {
        uint4 v = xp[t * (VPT / 8) + j];
        unsigned ws[4] = {v.x, v.y, v.z, v.w};
#pragma unroll
        for (int p = 0; p < 4; p++) {
            float f0 = gelu_exact(bf2f((unsigned short)(ws[p] & 0xffff)));
            float f1 = gelu_exact(bf2f((unsigned short)(ws[p] >> 16)));
            vals[8 * j + 2 * p] = f0; vals[8 * j + 2 * p + 1] = f1;
            ss += f0 * f0 + f1 * f1;
            am = fmaxf(am, fmaxf(fabsf(f0), fabsf(f1)));
        }
    }
    __shared__ float sp[8];
    __shared__ float bc[2];
    int wv = t >> 6, lane = t & 63;
    float S = waveSum(ss);
    float M = waveMax(am);
    if (lane == 0) { sp[wv] = S; sp[4 + wv] = M; }
    __syncthreads();
    if (t == 0) {
        float Sa = sp[0] + sp[1] + sp[2] + sp[3];
        float Ma = fmaxf(fmaxf(sp[4], sp[5]), fmaxf(sp[6], sp[7]));
        float rinv = rsqrtf(Sa * (1.f / (float)D) + EPSF);
        float amn = Ma * rinv;
        float scale = 127.f / fmaxf(amn, EPSF);
        rs_out[token] = 1.f / scale;
        bc[0] = rinv; bc[1] = scale;
    }
    __syncthreads();
    float rinv = bc[0], scale = bc[1];
    unsigned outw[4];
#pragma unroll
    for (int j = 0; j < VPT; j++) {
        float r = rintf((vals[j] * rinv) * scale);
        r = fminf(fmaxf(r, -128.f), 127.f);
        unsigned qi = (unsigned)((int)r & 0xff) << (8 * (j & 3));
        if ((j & 3) == 0) outw[j / 4] = qi; else outw[j / 4] |= qi;
    }
    uint4* qp = (uint4*)(Q + (long)token * D);
    qp[t] = make_uint4(outw[0], outw[1], outw[2], outw[3]);
}

// ---- int8 GEMM, 256x256 tile, BK=128, 8 waves (2M x 4N interleaved), 8-phase ----
// T3+T4+T5 port of the verified 256^2 8-phase schedule to i8 (BK=128 i8 is
// byte-identical to BK=64 bf16: 128 B/row, 16 KB half-tiles, 2 gload_lds/thread/phase).
//
// Interleaved wave tiling: wave (wmi,wni) owns rows {i*64+wmi*32} x cols {j*128+wni*32},
// so phase quadrant (ih,jh) touches exactly ONE A-half and ONE B-half. That makes
// current-buffer staging race-free after a half's last-read phase + barrier.
//
// Ring (per K-tile T, phase order (0,0),(1,0),(1,1),(0,1)):
//   p0: stage T+1.A0 (other buf)     reads: A0,B0
//   p1: stage T+1.B1 (other buf)     reads: A1      (B0 reused)
//   p2: stage T+2.B0 (cur buf; B0 last read p1, all reads drained by p1's barrier)
//                                    reads: B1      (A1 reused)
//   p3: stage T+2.A1 (cur buf; A1 last read p2)
//                                    reads: A0 again
// Boundary: s_waitcnt vmcnt(4)  -> T+1 fully landed, T+2.{B0,A1} stay in flight
// across the barrier (counted vmcnt, never 0 in the main loop).
// XOR swizzle slot^ (row&7) with pre-swizzled global source: column-slice
// ds_read_b128 spreads over all 8 bank groups (gload_lds dest stays linear).
template <int OUT_F32>
__global__ __launch_bounds__(512, 2) void gemm8_k(
    const char* __restrict__ A, const char* __restrict__ Bw,
    const float* __restrict__ rs, const float* __restrict__ wscale_p,
    const float* __restrict__ bias, void* __restrict__ outp,
    int M, int N, int K) {
    __shared__ char L[131072];  // A: [0,64K) = 2 bufs x 256row x 128B; B: [64K,128K)
    int t = threadIdx.x;
    int lane = t & 63, wv = t >> 6;
    int l31 = lane & 31, kh = lane >> 5;
    int wmi = wv >> 2, wni = wv & 3;
    int m0 = blockIdx.y * 256, n0 = blockIdx.x * 256;

    // staging: thread t covers row (c*64 + t>>3), phys slot t&7; source slot
    // pre-swizzled so linear LDS holds the swizzled layout.
    int srow = t >> 3;
    int scol = ((t & 7) ^ (srow & 7)) * 16;
    const char* srcA = A + (long)(m0 + srow) * K + scol;
    const char* srcB = Bw + (long)(n0 + srow) * K + scol;
    char* ldsA = L + (size_t)t * 16;
    char* ldsB = L + 65536 + (size_t)t * 16;
    long k64 = (long)64 * K;

    auto stA = [&](int Tt, int half) {
        const char* g = srcA + (long)(half * 128) * K + (long)Tt * 128;
        char* l = ldsA + (Tt & 1) * 32768 + half * 16384;
        async_copy16(g, l);
        async_copy16(g + k64, l + 8192);
    };
    auto stB = [&](int Tt, int half) {
        const char* g = srcB + (long)(half * 128) * K + (long)Tt * 128;
        char* l = ldsB + (Tt & 1) * 32768 + half * 16384;
        async_copy16(g, l);
        async_copy16(g + k64, l + 8192);
    };

    // fragment-read offsets (row&7 == l31&7 since all row terms are mult of 32)
    int slot[4];
#pragma unroll
    for (int ks = 0; ks < 4; ks++) slot[ks] = ((2 * ks + kh) ^ (l31 & 7)) * 16;
    int rowA[2][2], rowB[2];
#pragma unroll
    for (int ih = 0; ih < 2; ih++)
#pragma unroll
        for (int il = 0; il < 2; il++)
            rowA[ih][il] = (ih * 128 + il * 64 + wmi * 32 + l31) * 128;
#pragma unroll
    for (int jh = 0; jh < 2; jh++) rowB[jh] = 65536 + (jh * 128 + wni * 32 + l31) * 128;

    v16i acc[4][2] = {};
    int nK = K >> 7;

    // prologue: T0 complete + T1.B0 + T1.A1 (ring expects T1.{A0,B1} during T0)
    stA(0, 0); stA(0, 1); stB(0, 0); stB(0, 1);
    stB(1, 0); stA(1, 1);
    asm volatile("s_waitcnt vmcnt(4)" ::: "memory");  // T0 landed; T1.{B0,A1} in flight
    asm volatile("s_barrier" ::: "memory");

#pragma unroll 2
    for (int T = 0; T < nK; ++T) {
        int bo = (T & 1) * 32768;
        v4i a[2][4], bb[4];
        // ---- phase 0: read A(ih=0)+B(jh=0); stage T+1.A0 ----
#pragma unroll
        for (int il = 0; il < 2; il++)
#pragma unroll
            for (int ks = 0; ks < 4; ks++)
                a[il][ks] = *(const v4i*)(L + bo + rowA[0][il] + slot[ks]);
#pragma unroll
        for (int ks = 0; ks < 4; ks++)
            bb[ks] = *(const v4i*)(L + bo + rowB[0] + slot[ks]);
        if (T + 1 < nK) stA(T + 1, 0);
        asm volatile("s_barrier" ::: "memory");
        __builtin_amdgcn_s_setprio(1);
#pragma unroll
        for (int ks = 0; ks < 4; ks++) {
            acc[0][0] = __builtin_amdgcn_mfma_i32_32x32x32_i8(a[0][ks], bb[ks], acc[0][0], 0, 0, 0);
            acc[1][0] = __builtin_amdgcn_mfma_i32_32x32x32_i8(a[1][ks], bb[ks], acc[1][0], 0, 0, 0);
        }
        __builtin_amdgcn_s_setprio(0);
        asm volatile("s_barrier" ::: "memory");
        // ---- phase 1: read A(ih=1); stage T+1.B1 (B0 regs reused) ----
#pragma unroll
        for (int il = 0; il < 2; il++)
#pragma unroll
            for (int ks = 0; ks < 4; ks++)
                a[il][ks] = *(const v4i*)(L + bo + rowA[1][il] + slot[ks]);
        if (T + 1 < nK) stB(T + 1, 1);
        asm volatile("s_barrier" ::: "memory");
        __builtin_amdgcn_s_setprio(1);
#pragma unroll
        for (int ks = 0; ks < 4; ks++) {
            acc[2][0] = __builtin_amdgcn_mfma_i32_32x32x32_i8(a[0][ks], bb[ks], acc[2][0], 0, 0, 0);
            acc[3][0] = __builtin_amdgcn_mfma_i32_32x32x32_i8(a[1][ks], bb[ks], acc[3][0], 0, 0, 0);
        }
        __builtin_amdgcn_s_setprio(0);
        asm volatile("s_barrier" ::: "memory");
        // ---- phase 2: read B(jh=1); stage T+2.B0 (A1 regs reused) ----
#pragma unroll
        for (int ks = 0; ks < 4; ks++)
            bb[ks] = *(const v4i*)(L + bo + rowB[1] + slot[ks]);
        if (T + 2 < nK) stB(T + 2, 0);
        asm volatile("s_barrier" ::: "memory");
        __builtin_amdgcn_s_setprio(1);
#pragma unroll
        for (int ks = 0; ks < 4; ks++) {
            acc[2][1] = __builtin_amdgcn_mfma_i32_32x32x32_i8(a[0][ks], bb[ks], acc[2][1], 0, 0, 0);
            acc[3][1] = __builtin_amdgcn_mfma_i32_32x32x32_i8(a[1][ks], bb[ks], acc[3][1], 0, 0, 0);
        }
        __builtin_amdgcn_s_setprio(0);
        asm volatile("s_barrier" ::: "memory");
        // ---- phase 3: re-read A(ih=0); stage T+2.A1 (B1 regs reused) ----
#pragma unroll
        for (int il = 0; il < 2; il++)
#pragma unroll
            for (int ks = 0; ks < 4; ks++)
                a[il][ks] = *(const v4i*)(L + bo + rowA[0][il] + slot[ks]);
        if (T + 2 < nK) stA(T + 2, 1);
        asm volatile("s_barrier" ::: "memory");
        __builtin_amdgcn_s_setprio(1);
#pragma unroll
        for (int ks = 0; ks < 4; ks++) {
            acc[0][1] = __builtin_amdgcn_mfma_i32_32x32x32_i8(a[0][ks], bb[ks], acc[0][1], 0, 0, 0);
            acc[1][1] = __builtin_amdgcn_mfma_i32_32x32x32_i8(a[1][ks], bb[ks], acc[1][1], 0, 0, 0);
        }
        __builtin_amdgcn_s_setprio(0);
        // boundary: T+1 must be fully landed; keep T+2.{B0,A1} (4 loads) in flight
        asm volatile("s_waitcnt vmcnt(4)" ::: "memory");
        asm volatile("s_barrier" ::: "memory");
    }

    // Epilogue. 32x32 C/D layout: col = lane&31, row = (reg&3) + 8*(reg>>2) + 4*(lane>>5)
    float wsc = *wscale_p;
    float bv[2];
#pragma unroll
    for (int j = 0; j < 2; j++) bv[j] = bias[n0 + j * 128 + wni * 32 + l31];
#pragma unroll
    for (int i = 0; i < 4; i++) {
        int mbase = m0 + i * 64 + wmi * 32 + 4 * kh;
        float fsv[16];
#pragma unroll
        for (int rg = 0; rg < 16; rg++)
            fsv[rg] = rs[mbase + (rg & 3) + 8 * (rg >> 2)] * wsc;
#pragma unroll
        for (int j = 0; j < 2; j++) {
            int ng = n0 + j * 128 + wni * 32 + l31;
#pragma unroll
            for (int rg = 0; rg < 16; rg++) {
                int mg = mbase + (rg & 3) + 8 * (rg >> 2);
                float v = (float)acc[i][j][rg] * fsv[rg] + bv[j];
                long idx = (long)mg * N + ng;
                if (OUT_F32) ((float*)outp)[idx] = v;
                else ((unsigned short*)outp)[idx] = f2bf(v);
            }
        }
    }
}

extern "C" void kernel_launch(void* const* d_in, const int* in_sizes, int n_in,
                              void* d_out, int out_size, void* d_ws, size_t ws_size,
                              hipStream_t stream) {
    const float* x  = (const float*)d_in[0];
    const float* w1 = (const float*)d_in[1];
    const float* b1 = (const float*)d_in[2];
    const float* w2 = (const float*)d_in[3];
    const float* b2 = (const float*)d_in[4];
    float* out = (float*)d_out;

    char* ws = (char*)d_ws;
    float* acc1 = (float*)(ws + 0);
    float* acc2 = (float*)(ws + 4);
    float* wsc1 = (float*)(ws + 8);
    float* wsc2 = (float*)(ws + 12);
    size_t off = 256;
    char* w1q = ws + off; off += (size_t)INNER * DIM;        // 4 MB
    char* w2q = ws + off; off += (size_t)INNER * DIM;        // 4 MB
    char* xq1 = ws + off; off += (size_t)TOK * DIM;          // 16 MB
    float* rs1 = (float*)(ws + off); off += (size_t)TOK * 4; // 64 KB
    char* xq2 = ws + off; off += (size_t)TOK * INNER;        // 64 MB
    float* rs2 = (float*)(ws + off); off += (size_t)TOK * 4; // 64 KB
    unsigned short* h = (unsigned short*)(ws + off);         // 128 MB bf16 (pre-GELU now)

    hipMemsetAsync(d_ws, 0, 16, stream);

    int nw = INNER * DIM;
    absmean_k<<<1024, 256, 0, stream>>>(w1, nw / 4, acc1);
    absmean_k<<<1024, 256, 0, stream>>>(w2, nw / 4, acc2);
    wquant_k<<<2048, 256, 0, stream>>>(w1, nw, acc1, wsc1, w1q);
    wquant_k<<<2048, 256, 0, stream>>>(w2, nw, acc2, wsc2, w2q);

    actquant_f32_k<DIM, 4><<<TOK, 256, 0, stream>>>(x, xq1, rs1);
    gemm8_k<0><<<dim3(INNER / 256, TOK / 256), 512, 0, stream>>>(
        xq1, w1q, rs1, wsc1, b1, (void*)h, TOK, INNER, DIM);
    actquant_bf16_k<INNER, 16><<<TOK, 256, 0, stream>>>(h, xq2, rs2);
    gemm8_k<1><<<dim3(DIM / 256, TOK / 256), 512, 0, stream>>>(
        xq2, w2q, rs2, wsc2, b2, (void*)out, TOK, DIM, INNER);
}